// Round 1
// 257.991 us; speedup vs baseline: 1.0202x; 1.0202x over previous
//
#include <hip/hip_runtime.h>
#include <hip/hip_bf16.h>

// LinearAttention: B=8, C=512, L=4096, HEADS=8, dim_head=64, hidden=512
// R6: 256x256 8-phase deep-pipelined GEMM (guide §5 template: T3+T4 counted vmcnt,
//     T5 setprio, existing conflict-free XOR swizzle = T2) for the two big GEMMs
//     (kv = Wkv@x and out = W3@x). gemm3 (512^3) stays on the 128^2 kernel.
// Pipeline: prep_all; kv=GEMM256(wkv,xt); rowstat(k); ctx(k,stats,v); w2; W3=w2@Wq(128^2); out=GEMM256(W3,xt).

typedef __bf16 bf16x8 __attribute__((ext_vector_type(8)));
typedef __bf16 bf16x4 __attribute__((ext_vector_type(4)));
typedef float  f32x4  __attribute__((ext_vector_type(4)));

#define B_  8
#define L_  4096
#define C_  512

#define GLD_LDS16(g, l)                                             \
    __builtin_amdgcn_global_load_lds(                               \
        (const __attribute__((address_space(1))) void*)(g),         \
        (__attribute__((address_space(3))) void*)(l), 16, 0, 0)

#define FENCE asm volatile("" ::: "memory")
#define BAR   do { FENCE; __builtin_amdgcn_s_barrier(); FENCE; } while (0)
#define DRAIN_LGKM asm volatile("s_waitcnt lgkmcnt(0)" ::: "memory")
#define WAIT_VM(N) asm volatile("s_waitcnt vmcnt(" #N ")" ::: "memory")

// ---------------- prep_all: x-transpose+cvt | wkv cvt | WqT | ctx zero ----------------
__global__ __launch_bounds__(256) void prep_all(const float* __restrict__ x,
                                                __hip_bfloat16* __restrict__ xt,
                                                const float* __restrict__ wqkv_f,
                                                __hip_bfloat16* __restrict__ wkv_b,
                                                __hip_bfloat16* __restrict__ wqT,
                                                float* __restrict__ ctx) {
    __shared__ float tile[64 * 132];
    int blk = blockIdx.x;
    int t = threadIdx.x;
    if (blk < 2048) {
        // transpose fp32 x[b][C][L] -> bf16 xt[b][L][C]; 64c x 128l tile
        int b = blk >> 8, rem = blk & 255;
        int l0 = (rem & 31) * 128, c0 = (rem >> 5) * 64;
        const float* xp = x + ((size_t)b * C_ + c0) * L_ + l0;
#pragma unroll
        for (int p = 0; p < 8; p++) {
            int i = p * 8 + (t >> 5);
            int j = (t & 31) * 4;
            float4 vv = *(const float4*)(xp + (size_t)i * L_ + j);
            *(float4*)&tile[i * 132 + j] = vv;
        }
        __syncthreads();
        unsigned short* xo = (unsigned short*)xt + ((size_t)b * L_ + l0) * C_ + c0;
#pragma unroll
        for (int qq = 0; qq < 8; qq++) {
            int l = qq * 16 + (t >> 4);
            int cg = (t & 15) * 4;
            bf16x4 ov;
#pragma unroll
            for (int k = 0; k < 4; k++) ov[k] = (__bf16)tile[(cg + k) * 132 + l];
            *(bf16x4*)(xo + (size_t)l * C_ + cg) = ov;
        }
    } else if (blk < 4096) {
        int i = (blk - 2048) * 256 + t;  // 1024*512 elements (w_qkv rows 512..1535)
        wkv_b[i] = __float2bfloat16(wqkv_f[512 * 512 + i]);
    } else if (blk < 4352) {
        // wqT[c][c'] = w_qkv[c'][c] (q-part rows 0..511), bf16
        int tb = blk - 4096;
        int r0 = (tb >> 4) * 32, c0 = (tb & 15) * 32;
        int tx = t & 31, ty = t >> 5;
        for (int r = 0; r < 32; r += 8)
            tile[(ty + r) * 33 + tx] = wqkv_f[(size_t)(r0 + ty + r) * 512 + c0 + tx];
        __syncthreads();
        for (int r = 0; r < 32; r += 8)
            wqT[(size_t)(c0 + ty + r) * 512 + r0 + tx] = __float2bfloat16(tile[tx * 33 + ty + r]);
    } else {
        int i = (blk - 4352) * 256 + t;  // 262144 floats
        ctx[i] = 0.f;
    }
}

// ---------------- 128^2 GEMM (kept for the small 512^3 GEMM) ----------------
// C[M][N] = A[M][K] * Bt[N][K]^T, BK=64, MODE 3: out bf16
template <int MODE>
__global__ __launch_bounds__(256) void gemm_bt(
    const __hip_bfloat16* __restrict__ A, const __hip_bfloat16* __restrict__ Bt,
    size_t strideA, size_t strideB, int M, int N, int K,
    __hip_bfloat16* __restrict__ obf) {
    __shared__ alignas(16) unsigned short As[128 * 64];  // 16 KiB
    __shared__ alignas(16) unsigned short Bs[128 * 64];

    int b = blockIdx.z;
    int m0 = blockIdx.y * 128, n0 = blockIdx.x * 128;
    const __hip_bfloat16* Ab = A + strideA * (size_t)b;
    const __hip_bfloat16* Bb = Bt + strideB * (size_t)b;

    int t = threadIdx.x;
    int lane = t & 63, wv = t >> 6;
    int l16 = lane & 15, q4 = lane >> 4;
    int wr = (wv >> 1) * 64, wc = (wv & 1) * 64;

    int srow = lane >> 3;
    int swz  = ((lane & 7) ^ srow) * 8;

    const __hip_bfloat16* gA[4];
    const __hip_bfloat16* gB[4];
    unsigned short* lA[4];
    unsigned short* lB[4];
#pragma unroll
    for (int c = 0; c < 4; c++) {
        int r = wv * 32 + c * 8;
        gA[c] = Ab + (size_t)(m0 + r + srow) * K + swz;
        gB[c] = Bb + (size_t)(n0 + r + srow) * K + swz;
        lA[c] = &As[r * 64];
        lB[c] = &Bs[r * 64];
    }

    int gsel0 = ((q4) ^ (l16 & 7)) * 8;
    int gsel1 = ((4 + q4) ^ (l16 & 7)) * 8;
    int rA = (wr + l16) * 64;
    int rB = (wc + l16) * 64;

    f32x4 acc[4][4] = {};

    for (int k0 = 0; k0 < K; k0 += 64) {
        __syncthreads();
#pragma unroll
        for (int c = 0; c < 4; c++) {
            GLD_LDS16(gA[c] + k0, lA[c]);
            GLD_LDS16(gB[c] + k0, lB[c]);
        }
        __syncthreads();

        bf16x8 af[4], bfr[4];
#pragma unroll
        for (int i = 0; i < 4; i++) {
            af[i]  = *(const bf16x8*)&As[rA + i * 1024 + gsel0];
            bfr[i] = *(const bf16x8*)&Bs[rB + i * 1024 + gsel0];
        }
#pragma unroll
        for (int i = 0; i < 4; i++)
#pragma unroll
            for (int j = 0; j < 4; j++)
                acc[i][j] = __builtin_amdgcn_mfma_f32_16x16x32_bf16(af[i], bfr[j], acc[i][j], 0, 0, 0);
#pragma unroll
        for (int i = 0; i < 4; i++) {
            af[i]  = *(const bf16x8*)&As[rA + i * 1024 + gsel1];
            bfr[i] = *(const bf16x8*)&Bs[rB + i * 1024 + gsel1];
        }
#pragma unroll
        for (int i = 0; i < 4; i++)
#pragma unroll
            for (int j = 0; j < 4; j++)
                acc[i][j] = __builtin_amdgcn_mfma_f32_16x16x32_bf16(af[i], bfr[j], acc[i][j], 0, 0, 0);
    }

#pragma unroll
    for (int i = 0; i < 4; i++)
#pragma unroll
        for (int j = 0; j < 4; j++)
#pragma unroll
            for (int r = 0; r < 4; r++) {
                int row = m0 + wr + i * 16 + q4 * 4 + r;
                int col = n0 + wc + j * 16 + l16;
                obf[((size_t)b * 512 + row) * (size_t)N + col] = __float2bfloat16(acc[i][j][r]);
            }
}

// ---------------- 256^2 8-phase deep-pipelined GEMM ----------------
// C[M][N] = A[M][K] * Bt[N][K]^T.  BM=BN=256, BK=64, 512 thr (2x4 waves),
// per-wave C = 128x64 (8 m-frags x 4 n-frags).  LDS 128 KiB (2 dbuf x (A+B)).
// Schedule per K-tile kt (4 phases, quadrants of the wave's C, full K=64 each):
//   p0: ds_read a[0-3](both ks) + b[0-1]; stage A-rows128-255 of kt+1 (other buf)
//   p1: ds_read b[2-3];                   stage B-rows0-127  of kt+1
//   p2: ds_read a[4-7] (reuse regs);      stage B-rows128-255 of kt+1
//   p3: (no reads)                        stage A-rows0-127  of kt+2 (SAME buf;
//        that region's last read was p2, behind a barrier) ; vmcnt(2) ; barrier
// vmcnt(2) leaves kt+2's first half-tile in flight -> no drain in main loop (T4).
// Per-phase: reads+stage -> barrier -> setprio(1) MFMA x16 setprio(0) ->
//            lgkmcnt(0) (WAR guard) -> barrier.
// MODE 1: M=1024, rows 0-511 -> kb bf16 [b][512][N], 512-1023 -> vb
// MODE 2: out fp32 [b][M][N] + bias[M]
template <int MODE>
__global__ __launch_bounds__(512, 2) void gemm256(
    const __hip_bfloat16* __restrict__ A, const __hip_bfloat16* __restrict__ Bt,
    size_t strideA, size_t strideB, int M, int N, int K,
    __hip_bfloat16* __restrict__ kb, __hip_bfloat16* __restrict__ vb,
    float* __restrict__ outb, const float* __restrict__ bias) {
    __shared__ alignas(16) unsigned short sA[2][256 * 64];  // 64 KiB
    __shared__ alignas(16) unsigned short sB[2][256 * 64];  // 64 KiB

    int b = blockIdx.z;
    int m0 = blockIdx.y * 256, n0 = blockIdx.x * 256;
    const __hip_bfloat16* Ab = A + strideA * (size_t)b;
    const __hip_bfloat16* Bb = Bt + strideB * (size_t)b;

    int t = threadIdx.x;
    int lane = t & 63, wv = t >> 6;
    int l16 = lane & 15, q4 = lane >> 4;
    int wm = wv >> 2, wn = wv & 3;

    // staging: one source GLD = 512 thr x 16B = 64 rows of 128B. lane -> (row=lane>>3, grp=lane&7)
    int srow = lane >> 3;
    int swz  = ((lane & 7) ^ srow) * 8;  // LDS grp g of row r holds k-group g^(r&7)

    const __hip_bfloat16* gA[4];
    const __hip_bfloat16* gB[4];
    unsigned ldoff[4];
#pragma unroll
    for (int c = 0; c < 4; c++) {
        gA[c] = Ab + (size_t)(m0 + c * 64 + wv * 8 + srow) * K + swz;
        gB[c] = Bb + (size_t)(n0 + c * 64 + wv * 8 + srow) * K + swz;
        ldoff[c] = (unsigned)(c * 64 + wv * 8) * 64;
    }

    int gsel0 = (q4 ^ (l16 & 7)) * 8;
    int gsel1 = gsel0 ^ 32;
    unsigned offA = (unsigned)(wm * 128 + l16) * 64;
    unsigned offB = (unsigned)(wn * 64 + l16) * 64;
    int NKT = K >> 6;

    f32x4 acc[8][4] = {};
    bf16x8 aF[4][2], bF[4][2];

    // prologue: tile0 fully + tile1 A-rows0-127; allow the latter 2 in flight
#pragma unroll
    for (int c = 0; c < 4; c++) GLD_LDS16(gA[c], &sA[0][ldoff[c]]);
#pragma unroll
    for (int c = 0; c < 4; c++) GLD_LDS16(gB[c], &sB[0][ldoff[c]]);
    if (NKT > 1) {
        GLD_LDS16(gA[0] + 64, &sA[1][ldoff[0]]);
        GLD_LDS16(gA[1] + 64, &sA[1][ldoff[1]]);
        WAIT_VM(2);
    } else {
        WAIT_VM(0);
    }
    BAR;

#pragma unroll 1
    for (int kt = 0; kt < NKT; ++kt) {
        const unsigned short* As_b = sA[kt & 1];
        const unsigned short* Bs_b = sB[kt & 1];
        int nbuf = (kt + 1) & 1;
        int koff1 = (kt + 1) << 6;
        bool st1 = (kt + 1) < NKT;
        bool st2 = (kt + 2) < NKT;

        // ---- phase 0: Q0 = acc[0-3][0-1]
#pragma unroll
        for (int i = 0; i < 4; i++) {
            aF[i][0] = *(const bf16x8*)&As_b[offA + i * 1024 + gsel0];
            aF[i][1] = *(const bf16x8*)&As_b[offA + i * 1024 + gsel1];
        }
#pragma unroll
        for (int j = 0; j < 2; j++) {
            bF[j][0] = *(const bf16x8*)&Bs_b[offB + j * 1024 + gsel0];
            bF[j][1] = *(const bf16x8*)&Bs_b[offB + j * 1024 + gsel1];
        }
        if (st1) {
            GLD_LDS16(gA[2] + koff1, &sA[nbuf][ldoff[2]]);
            GLD_LDS16(gA[3] + koff1, &sA[nbuf][ldoff[3]]);
        }
        BAR;
        __builtin_amdgcn_s_setprio(1);
#pragma unroll
        for (int ks = 0; ks < 2; ks++)
#pragma unroll
            for (int i = 0; i < 4; i++)
#pragma unroll
                for (int j = 0; j < 2; j++)
                    acc[i][j] = __builtin_amdgcn_mfma_f32_16x16x32_bf16(aF[i][ks], bF[j][ks], acc[i][j], 0, 0, 0);
        __builtin_amdgcn_s_setprio(0);
        DRAIN_LGKM;
        BAR;

        // ---- phase 1: Q1 = acc[0-3][2-3]
#pragma unroll
        for (int j = 2; j < 4; j++) {
            bF[j][0] = *(const bf16x8*)&Bs_b[offB + j * 1024 + gsel0];
            bF[j][1] = *(const bf16x8*)&Bs_b[offB + j * 1024 + gsel1];
        }
        if (st1) {
            GLD_LDS16(gB[0] + koff1, &sB[nbuf][ldoff[0]]);
            GLD_LDS16(gB[1] + koff1, &sB[nbuf][ldoff[1]]);
        }
        BAR;
        __builtin_amdgcn_s_setprio(1);
#pragma unroll
        for (int ks = 0; ks < 2; ks++)
#pragma unroll
            for (int i = 0; i < 4; i++)
#pragma unroll
                for (int j = 0; j < 2; j++)
                    acc[i][2 + j] = __builtin_amdgcn_mfma_f32_16x16x32_bf16(aF[i][ks], bF[2 + j][ks], acc[i][2 + j], 0, 0, 0);
        __builtin_amdgcn_s_setprio(0);
        DRAIN_LGKM;
        BAR;

        // ---- phase 2: Q2 = acc[4-7][0-1] (a-regs reloaded with m-frags 4-7)
#pragma unroll
        for (int i = 0; i < 4; i++) {
            aF[i][0] = *(const bf16x8*)&As_b[offA + 4096 + i * 1024 + gsel0];
            aF[i][1] = *(const bf16x8*)&As_b[offA + 4096 + i * 1024 + gsel1];
        }
        if (st1) {
            GLD_LDS16(gB[2] + koff1, &sB[nbuf][ldoff[2]]);
            GLD_LDS16(gB[3] + koff1, &sB[nbuf][ldoff[3]]);
        }
        BAR;
        __builtin_amdgcn_s_setprio(1);
#pragma unroll
        for (int ks = 0; ks < 2; ks++)
#pragma unroll
            for (int i = 0; i < 4; i++)
#pragma unroll
                for (int j = 0; j < 2; j++)
                    acc[4 + i][j] = __builtin_amdgcn_mfma_f32_16x16x32_bf16(aF[i][ks], bF[j][ks], acc[4 + i][j], 0, 0, 0);
        __builtin_amdgcn_s_setprio(0);
        DRAIN_LGKM;
        BAR;

        // ---- phase 3: Q3 = acc[4-7][2-3]; stage kt+2 A-rows0-127 into SAME buffer
        if (st2) {
            int koff2 = (kt + 2) << 6;
            GLD_LDS16(gA[0] + koff2, &sA[kt & 1][ldoff[0]]);
            GLD_LDS16(gA[1] + koff2, &sA[kt & 1][ldoff[1]]);
        }
        BAR;
        __builtin_amdgcn_s_setprio(1);
#pragma unroll
        for (int ks = 0; ks < 2; ks++)
#pragma unroll
            for (int i = 0; i < 4; i++)
#pragma unroll
                for (int j = 0; j < 2; j++)
                    acc[4 + i][2 + j] = __builtin_amdgcn_mfma_f32_16x16x32_bf16(aF[i][ks], bF[2 + j][ks], acc[4 + i][2 + j], 0, 0, 0);
        __builtin_amdgcn_s_setprio(0);
        DRAIN_LGKM;
        if (st2) { WAIT_VM(2); } else { WAIT_VM(0); }
        BAR;
    }

    // epilogue: D row = q4*4 + r (within 16), col = l16
    int row0 = m0 + wm * 128, col0 = n0 + wn * 64;
    if (MODE == 1) {
        __hip_bfloat16* dst = (row0 < 512) ? kb : vb;  // block/wave-uniform (256-tile never straddles)
        int ob = row0 & 511;
#pragma unroll
        for (int i = 0; i < 8; i++)
#pragma unroll
            for (int j = 0; j < 4; j++)
#pragma unroll
                for (int r = 0; r < 4; r++) {
                    int od  = ob + i * 16 + q4 * 4 + r;
                    int col = col0 + j * 16 + l16;
                    dst[((size_t)b * 512 + od) * (size_t)N + col] = __float2bfloat16(acc[i][j][r]);
                }
    } else {
#pragma unroll
        for (int i = 0; i < 8; i++)
#pragma unroll
            for (int j = 0; j < 4; j++)
#pragma unroll
                for (int r = 0; r < 4; r++) {
                    int row = row0 + i * 16 + q4 * 4 + r;
                    int col = col0 + j * 16 + l16;
                    outb[((size_t)b * M + row) * (size_t)N + col] = acc[i][j][r] + bias[row];
                }
    }
}

// ---------------- rowstat: per-row max and 1/sum(exp) of k ----------------
__global__ __launch_bounds__(256) void rowstat(const __hip_bfloat16* __restrict__ kin,
                                               float* __restrict__ mrow,
                                               float* __restrict__ isrow) {
    int row = blockIdx.x;  // 0..4095
    const unsigned short* kp = (const unsigned short*)kin + (size_t)row * L_;
    __shared__ float buf[L_];
    __shared__ float red[8];
    int t = threadIdx.x, lane = t & 63, wv = t >> 6;
    float m = -1e30f;
    for (int i0 = t * 8; i0 < L_; i0 += 256 * 8) {
        bf16x8 kv = *(const bf16x8*)(kp + i0);
#pragma unroll
        for (int j = 0; j < 8; j++) {
            float xx = (float)kv[j];
            buf[i0 + j] = xx;
            m = fmaxf(m, xx);
        }
    }
    for (int o = 32; o; o >>= 1) m = fmaxf(m, __shfl_xor(m, o, 64));
    if (lane == 0) red[wv] = m;
    __syncthreads();
    m = fmaxf(fmaxf(red[0], red[1]), fmaxf(red[2], red[3]));
    float s = 0.f;
    for (int i = t; i < L_; i += 256) s += __expf(buf[i] - m);
    for (int o = 32; o; o >>= 1) s += __shfl_xor(s, o, 64);
    if (lane == 0) red[4 + wv] = s;
    __syncthreads();
    if (t == 0) {
        s = red[4] + red[5] + red[6] + red[7];
        mrow[row] = m;
        isrow[row] = 1.0f / s;
    }
}

// ---------------- ctx[b,h,d,e] = sum_n softmax(k)[d,n]*v[e,n], split-K x8 ----------------
__global__ __launch_bounds__(256) void ctx_kernel(const __hip_bfloat16* __restrict__ kraw,
                                                  const float* __restrict__ mrow,
                                                  const float* __restrict__ isrow,
                                                  const __hip_bfloat16* __restrict__ v,
                                                  float* __restrict__ ctx) {
    int kc = blockIdx.x, h = blockIdx.y, b = blockIdx.z;
    int t = threadIdx.x, lane = t & 63, wv = t >> 6;
    int l16 = lane & 15, q4 = lane >> 4;
    const __hip_bfloat16* ka = kraw + ((size_t)b * 512 + h * 64) * L_;
    const __hip_bfloat16* va = v + ((size_t)b * 512 + h * 64) * L_;
    int rbase = b * 512 + h * 64;
    float mr[4], ir[4];
#pragma unroll
    for (int i = 0; i < 4; i++) {
        mr[i] = mrow[rbase + i * 16 + l16];
        ir[i] = isrow[rbase + i * 16 + l16];
    }
    f32x4 acc[4][4] = {};
    int nbase = kc * 512 + wv * 128;
#pragma unroll
    for (int s = 0; s < 4; s++) {
        int n = nbase + s * 32 + q4 * 8;
        bf16x8 af[4], bfr[4];
#pragma unroll
        for (int i = 0; i < 4; i++) {
            bf16x8 kv = *(const bf16x8*)(ka + (size_t)(i * 16 + l16) * L_ + n);
#pragma unroll
            for (int e = 0; e < 8; e++)
                af[i][e] = (__bf16)(__expf((float)kv[e] - mr[i]) * ir[i]);
            bfr[i] = *(const bf16x8*)(va + (size_t)(i * 16 + l16) * L_ + n);
        }
#pragma unroll
        for (int i = 0; i < 4; i++)
#pragma unroll
            for (int j = 0; j < 4; j++)
                acc[i][j] = __builtin_amdgcn_mfma_f32_16x16x32_bf16(af[i], bfr[j], acc[i][j], 0, 0, 0);
    }
    __shared__ float cbuf[4096];
    for (int w = 0; w < 4; w++) {
        if (wv == w) {
#pragma unroll
            for (int i = 0; i < 4; i++)
#pragma unroll
                for (int j = 0; j < 4; j++)
#pragma unroll
                    for (int r = 0; r < 4; r++) {
                        int mm = i * 16 + q4 * 4 + r, nn = j * 16 + l16;
                        float pv = acc[i][j][r];
                        if (w == 0) cbuf[mm * 64 + nn] = pv;
                        else        cbuf[mm * 64 + nn] += pv;
                    }
        }
        __syncthreads();
    }
    float* cg = ctx + ((size_t)b * 8 + h) * 4096;
    for (int i = t; i < 4096; i += 256) atomicAdd(&cg[i], cbuf[i]);
}

// ---------------- w2[b][o][h*64+d] = sum_e w_out[o][h*64+e]*ctx[b,h,d,e] ----------------
__global__ __launch_bounds__(256) void w2_kernel(const float* __restrict__ wout,
                                                 const float* __restrict__ ctx,
                                                 __hip_bfloat16* __restrict__ w2) {
    int ob = blockIdx.x, h = blockIdx.y, b = blockIdx.z;
    __shared__ float cT[64 * 65];  // [e][d]
    __shared__ float wT[64 * 65];  // [e][ol]
    int t = threadIdx.x;
    const float* cg = ctx + ((size_t)b * 8 + h) * 4096;
    for (int i = t; i < 4096; i += 256) {
        int d = i >> 6, e = i & 63;
        cT[e * 65 + d] = cg[i];
        wT[e * 65 + d] = wout[(size_t)(ob * 64 + d) * 512 + h * 64 + e];
    }
    __syncthreads();
    int ol = t >> 2;
    int db = (t & 3) * 16;
    for (int dd = 0; dd < 16; dd++) {
        int d = db + dd;
        float s = 0.f;
#pragma unroll
        for (int e = 0; e < 64; e++) s += wT[e * 65 + ol] * cT[e * 65 + d];
        w2[((size_t)b * 512 + ob * 64 + ol) * 512 + h * 64 + d] = __float2bfloat16(s);
    }
}

// ---------------- launch ----------------
extern "C" void kernel_launch(void* const* d_in, const int* in_sizes, int n_in,
                              void* d_out, int out_size, void* d_ws, size_t ws_size,
                              hipStream_t stream) {
    const float* x     = (const float*)d_in[0];
    const float* w_qkv = (const float*)d_in[1];
    const float* w_out = (const float*)d_in[2];
    const float* b_out = (const float*)d_in[3];
    float* out = (float*)d_out;
    char* ws = (char*)d_ws;

    const size_t QKV = (size_t)B_ * 512 * L_;
    size_t off_xt  = 0;                                   // bf16 [b][L][C]   32 MiB
    size_t off_wkv = off_xt + (size_t)B_ * L_ * C_ * 2;   // bf16 1024x512     1 MiB
    size_t off_wqT = off_wkv + (size_t)1024 * 512 * 2;    // bf16 512x512    0.5 MiB
    size_t off_k   = off_wqT + (size_t)512 * 512 * 2;     // bf16             32 MiB
    size_t off_v   = off_k + QKV * 2;                     // bf16             32 MiB
    size_t off_ms  = off_v + QKV * 2;                     // fp32 4096        16 KiB
    size_t off_is  = off_ms + 4096 * 4;                   // fp32 4096        16 KiB
    size_t off_ctx = off_is + 4096 * 4;                   // fp32              1 MiB
    size_t off_w2  = off_ctx + (size_t)B_ * 8 * 64 * 64 * 4;   // bf16         4 MiB
    size_t off_w3  = off_w2 + (size_t)B_ * 512 * 512 * 2;      // bf16         4 MiB

    __hip_bfloat16* xt   = (__hip_bfloat16*)(ws + off_xt);
    __hip_bfloat16* wkvb = (__hip_bfloat16*)(ws + off_wkv);
    __hip_bfloat16* wqT  = (__hip_bfloat16*)(ws + off_wqT);
    __hip_bfloat16* kb   = (__hip_bfloat16*)(ws + off_k);
    __hip_bfloat16* vb   = (__hip_bfloat16*)(ws + off_v);
    float*          ms   = (float*)(ws + off_ms);
    float*          isv  = (float*)(ws + off_is);
    float*          ctx  = (float*)(ws + off_ctx);
    __hip_bfloat16* w2   = (__hip_bfloat16*)(ws + off_w2);
    __hip_bfloat16* W3   = (__hip_bfloat16*)(ws + off_w3);

    prep_all<<<5376, 256, 0, stream>>>(x, xt, w_qkv, wkvb, wqT, ctx);

    // k,v = Wkv @ x   (M=1024, N=4096, K=512 per batch) — 256^2 8-phase
    gemm256<1><<<dim3(L_ / 256, 1024 / 256, B_), 512, 0, stream>>>(
        wkvb, xt, 0, (size_t)L_ * C_, 1024, L_, 512, kb, vb, nullptr, nullptr);

    rowstat<<<B_ * 512, 256, 0, stream>>>(kb, ms, isv);
    ctx_kernel<<<dim3(8, 8, B_), 256, 0, stream>>>(kb, ms, isv, vb, ctx);
    w2_kernel<<<dim3(8, 8, B_), 256, 0, stream>>>(w_out, ctx, w2);

    // W3[b] = w2[b] @ Wq   (M=512, N=512, K=512) — small, keep 128^2
    gemm_bt<3><<<dim3(512 / 128, 512 / 128, B_), 256, 0, stream>>>(
        w2, wqT, (size_t)512 * 512, 0, 512, 512, 512, W3);

    // out = W3[b] @ x[b] + b_out   (M=512, N=4096, K=512) — 256^2 8-phase
    gemm256<2><<<dim3(L_ / 256, 512 / 256, B_), 512, 0, stream>>>(
        W3, xt, (size_t)512 * 512, (size_t)L_ * C_, 512, L_, 512, nullptr, nullptr, out, b_out);
}

// Round 2
// 244.398 us; speedup vs baseline: 1.0770x; 1.0556x over previous
//
#include <hip/hip_runtime.h>
#include <hip/hip_bf16.h>

// LinearAttention: B=8, C=512, L=4096, HEADS=8, dim_head=64, hidden=512
// R7: (a) big GEMMs -> pipelined 128^2 tile, 2 blocks/CU (latency hiding via
//     concurrency + 8-way B-panel sharing), counted-vmcnt 2-phase schedule.
//     (b) rowstat deleted: ctx accumulates unnormalized exp(k)@v^T + row-sums
//     (kc=4 partials, no atomics, no zeroing); w2 sums partials & normalizes.
// Pipeline: prep_all; kv=gemm_p(wkv,xt); ctx(k,v); w2; W3=w2@Wq(gemm_bt); out=gemm_p(W3,xt).

typedef __bf16 bf16x8 __attribute__((ext_vector_type(8)));
typedef __bf16 bf16x4 __attribute__((ext_vector_type(4)));
typedef float  f32x4  __attribute__((ext_vector_type(4)));

#define B_  8
#define L_  4096
#define C_  512

#define GLD_LDS16(g, l)                                             \
    __builtin_amdgcn_global_load_lds(                               \
        (const __attribute__((address_space(1))) void*)(g),         \
        (__attribute__((address_space(3))) void*)(l), 16, 0, 0)

#define FENCE asm volatile("" ::: "memory")
#define BAR   do { FENCE; __builtin_amdgcn_s_barrier(); FENCE; } while (0)
#define DRAIN_LGKM asm volatile("s_waitcnt lgkmcnt(0)" ::: "memory")
#define WAIT_VM(N) asm volatile("s_waitcnt vmcnt(" #N ")" ::: "memory")

// ---------------- prep_all: x-transpose+cvt | wkv cvt | WqT ----------------
__global__ __launch_bounds__(256) void prep_all(const float* __restrict__ x,
                                                __hip_bfloat16* __restrict__ xt,
                                                const float* __restrict__ wqkv_f,
                                                __hip_bfloat16* __restrict__ wkv_b,
                                                __hip_bfloat16* __restrict__ wqT) {
    __shared__ float tile[64 * 132];
    int blk = blockIdx.x;
    int t = threadIdx.x;
    if (blk < 2048) {
        // transpose fp32 x[b][C][L] -> bf16 xt[b][L][C]; 64c x 128l tile
        int b = blk >> 8, rem = blk & 255;
        int l0 = (rem & 31) * 128, c0 = (rem >> 5) * 64;
        const float* xp = x + ((size_t)b * C_ + c0) * L_ + l0;
#pragma unroll
        for (int p = 0; p < 8; p++) {
            int i = p * 8 + (t >> 5);
            int j = (t & 31) * 4;
            float4 vv = *(const float4*)(xp + (size_t)i * L_ + j);
            *(float4*)&tile[i * 132 + j] = vv;
        }
        __syncthreads();
        unsigned short* xo = (unsigned short*)xt + ((size_t)b * L_ + l0) * C_ + c0;
#pragma unroll
        for (int qq = 0; qq < 8; qq++) {
            int l = qq * 16 + (t >> 4);
            int cg = (t & 15) * 4;
            bf16x4 ov;
#pragma unroll
            for (int k = 0; k < 4; k++) ov[k] = (__bf16)tile[(cg + k) * 132 + l];
            *(bf16x4*)(xo + (size_t)l * C_ + cg) = ov;
        }
    } else if (blk < 4096) {
        int i = (blk - 2048) * 256 + t;  // 1024*512 elements (w_qkv rows 512..1535)
        wkv_b[i] = __float2bfloat16(wqkv_f[512 * 512 + i]);
    } else {
        // wqT[c][c'] = w_qkv[c'][c] (q-part rows 0..511), bf16
        int tb = blk - 4096;
        int r0 = (tb >> 4) * 32, c0 = (tb & 15) * 32;
        int tx = t & 31, ty = t >> 5;
        for (int r = 0; r < 32; r += 8)
            tile[(ty + r) * 33 + tx] = wqkv_f[(size_t)(r0 + ty + r) * 512 + c0 + tx];
        __syncthreads();
        for (int r = 0; r < 32; r += 8)
            wqT[(size_t)(c0 + ty + r) * 512 + r0 + tx] = __float2bfloat16(tile[tx * 33 + ty + r]);
    }
}

// ---------------- pipelined 128^2 GEMM, 2 blocks/CU ----------------
// C[M][N] = A[M][K] * Bt[N][K]^T.  BM=BN=128, BK=64, 256 thr (2x2 waves),
// per-wave C = 64x64 (4x4 frags).  LDS 64 KiB/block -> 2 blocks/CU.
// LDS rows 128B; 16B group g of row r holds k-group g^(r&7) (conflict-free b128).
// Schedule per K-tile kt (2 phases):
//   p0: ds_read a[0-3](2ks) + b[0-1]; stage B(kt+1) -> other buf
//   p1: ds_read b[2-3];               stage A(kt+2) -> SAME buf (A last read p0,
//       drained by lgkmcnt before p0's closing barrier); vmcnt(4) (A(kt+2) stays
//       in flight); barrier.
// Steady-state outstanding after boundary = 4 (next tile's A). Never vmcnt(0)
// mid-loop (T4).
// MODE 1: M=1024: rows 0-511 -> kb bf16 [b][512][N], 512-1023 -> vb
// MODE 2: out fp32 [b][M][N] + bias[M]
template <int MODE>
__global__ __launch_bounds__(256, 2) void gemm_p(
    const __hip_bfloat16* __restrict__ A, const __hip_bfloat16* __restrict__ Bt,
    size_t strideA, size_t strideB, int M, int N, int K,
    __hip_bfloat16* __restrict__ kb, __hip_bfloat16* __restrict__ vb,
    float* __restrict__ outb, const float* __restrict__ bias) {
    __shared__ alignas(16) unsigned short sA[2][128 * 64];  // 32 KiB
    __shared__ alignas(16) unsigned short sB[2][128 * 64];  // 32 KiB

    int b = blockIdx.z;
    int m0 = blockIdx.y * 128, n0 = blockIdx.x * 128;
    const __hip_bfloat16* Ab = A + strideA * (size_t)b;
    const __hip_bfloat16* Bb = Bt + strideB * (size_t)b;

    int t = threadIdx.x;
    int lane = t & 63, wv = t >> 6;
    int l16 = lane & 15, q4 = lane >> 4;
    int wr = (wv >> 1) * 64, wc = (wv & 1) * 64;

    // staging: one GLD inst = 256 thr x 16B = 32 rows of 128B; per wave 8 rows.
    int srow = lane >> 3;
    int swz  = ((lane & 7) ^ srow) * 8;

    const __hip_bfloat16* gA[4];
    const __hip_bfloat16* gB[4];
    unsigned ldoff[4];
#pragma unroll
    for (int c = 0; c < 4; c++) {
        int r = c * 32 + wv * 8;
        gA[c] = Ab + (size_t)(m0 + r + srow) * K + swz;
        gB[c] = Bb + (size_t)(n0 + r + srow) * K + swz;
        ldoff[c] = (unsigned)r * 64;
    }

    int gsel0 = (q4 ^ (l16 & 7)) * 8;
    int gsel1 = gsel0 ^ 32;
    unsigned rA = (unsigned)(wr + l16) * 64;
    unsigned rB = (unsigned)(wc + l16) * 64;
    int NKT = K >> 6;

    f32x4 acc[4][4] = {};
    bf16x8 aF[4][2], bF[4][2];

    // prologue: tile0 A+B, tile1 A; leave tile1 A (4) in flight
#pragma unroll
    for (int c = 0; c < 4; c++) GLD_LDS16(gA[c], &sA[0][ldoff[c]]);
#pragma unroll
    for (int c = 0; c < 4; c++) GLD_LDS16(gB[c], &sB[0][ldoff[c]]);
    if (NKT > 1) {
#pragma unroll
        for (int c = 0; c < 4; c++) GLD_LDS16(gA[c] + 64, &sA[1][ldoff[c]]);
        WAIT_VM(4);
    } else {
        WAIT_VM(0);
    }
    BAR;

#pragma unroll 1
    for (int kt = 0; kt < NKT; ++kt) {
        int cur = kt & 1, nbuf = cur ^ 1;
        const unsigned short* As_b = sA[cur];
        const unsigned short* Bs_b = sB[cur];
        bool st1 = (kt + 1) < NKT;
        bool st2 = (kt + 2) < NKT;

        // ---- phase 0: acc[0-3][0-1]
#pragma unroll
        for (int i = 0; i < 4; i++) {
            aF[i][0] = *(const bf16x8*)&As_b[rA + i * 1024 + gsel0];
            aF[i][1] = *(const bf16x8*)&As_b[rA + i * 1024 + gsel1];
        }
#pragma unroll
        for (int j = 0; j < 2; j++) {
            bF[j][0] = *(const bf16x8*)&Bs_b[rB + j * 1024 + gsel0];
            bF[j][1] = *(const bf16x8*)&Bs_b[rB + j * 1024 + gsel1];
        }
        if (st1) {
            int ko = (kt + 1) << 6;
#pragma unroll
            for (int c = 0; c < 4; c++) GLD_LDS16(gB[c] + ko, &sB[nbuf][ldoff[c]]);
        }
        BAR;
        __builtin_amdgcn_s_setprio(1);
#pragma unroll
        for (int ks = 0; ks < 2; ks++)
#pragma unroll
            for (int i = 0; i < 4; i++)
#pragma unroll
                for (int j = 0; j < 2; j++)
                    acc[i][j] = __builtin_amdgcn_mfma_f32_16x16x32_bf16(aF[i][ks], bF[j][ks], acc[i][j], 0, 0, 0);
        __builtin_amdgcn_s_setprio(0);
        DRAIN_LGKM;
        BAR;

        // ---- phase 1: acc[0-3][2-3]; stage A(kt+2) into SAME buffer
#pragma unroll
        for (int j = 2; j < 4; j++) {
            bF[j][0] = *(const bf16x8*)&Bs_b[rB + j * 1024 + gsel0];
            bF[j][1] = *(const bf16x8*)&Bs_b[rB + j * 1024 + gsel1];
        }
        if (st2) {
            int ko = (kt + 2) << 6;
#pragma unroll
            for (int c = 0; c < 4; c++) GLD_LDS16(gA[c] + ko, &sA[cur][ldoff[c]]);
        }
        BAR;
        __builtin_amdgcn_s_setprio(1);
#pragma unroll
        for (int ks = 0; ks < 2; ks++)
#pragma unroll
            for (int i = 0; i < 4; i++)
#pragma unroll
                for (int j = 0; j < 2; j++)
                    acc[i][2 + j] = __builtin_amdgcn_mfma_f32_16x16x32_bf16(aF[i][ks], bF[2 + j][ks], acc[i][2 + j], 0, 0, 0);
        __builtin_amdgcn_s_setprio(0);
        DRAIN_LGKM;
        if (st2) { WAIT_VM(4); } else { WAIT_VM(0); }
        BAR;
    }

    // epilogue: D row = q4*4 + r (within 16), col = l16
#pragma unroll
    for (int i = 0; i < 4; i++)
#pragma unroll
        for (int j = 0; j < 4; j++)
#pragma unroll
            for (int r = 0; r < 4; r++) {
                int row = m0 + wr + i * 16 + q4 * 4 + r;
                int col = n0 + wc + j * 16 + l16;
                float val = acc[i][j][r];
                if (MODE == 1) {
                    __hip_bfloat16* dst = (m0 < 512) ? kb : vb;  // 128-tile never straddles
                    int od = row & 511;
                    dst[((size_t)b * 512 + od) * (size_t)N + col] = __float2bfloat16(val);
                } else {
                    outb[((size_t)b * M + row) * (size_t)N + col] = val + bias[row];
                }
            }
}

// ---------------- 128^2 GEMM (small 512^3 GEMM), MODE 3: out bf16 ----------------
template <int MODE>
__global__ __launch_bounds__(256) void gemm_bt(
    const __hip_bfloat16* __restrict__ A, const __hip_bfloat16* __restrict__ Bt,
    size_t strideA, size_t strideB, int M, int N, int K,
    __hip_bfloat16* __restrict__ obf) {
    __shared__ alignas(16) unsigned short As[128 * 64];
    __shared__ alignas(16) unsigned short Bs[128 * 64];

    int b = blockIdx.z;
    int m0 = blockIdx.y * 128, n0 = blockIdx.x * 128;
    const __hip_bfloat16* Ab = A + strideA * (size_t)b;
    const __hip_bfloat16* Bb = Bt + strideB * (size_t)b;

    int t = threadIdx.x;
    int lane = t & 63, wv = t >> 6;
    int l16 = lane & 15, q4 = lane >> 4;
    int wr = (wv >> 1) * 64, wc = (wv & 1) * 64;

    int srow = lane >> 3;
    int swz  = ((lane & 7) ^ srow) * 8;

    const __hip_bfloat16* gA[4];
    const __hip_bfloat16* gB[4];
    unsigned short* lA[4];
    unsigned short* lB[4];
#pragma unroll
    for (int c = 0; c < 4; c++) {
        int r = wv * 32 + c * 8;
        gA[c] = Ab + (size_t)(m0 + r + srow) * K + swz;
        gB[c] = Bb + (size_t)(n0 + r + srow) * K + swz;
        lA[c] = &As[r * 64];
        lB[c] = &Bs[r * 64];
    }

    int gsel0 = ((q4) ^ (l16 & 7)) * 8;
    int gsel1 = gsel0 ^ 32;
    int rA = (wr + l16) * 64;
    int rB = (wc + l16) * 64;

    f32x4 acc[4][4] = {};

    for (int k0 = 0; k0 < K; k0 += 64) {
        __syncthreads();
#pragma unroll
        for (int c = 0; c < 4; c++) {
            GLD_LDS16(gA[c] + k0, lA[c]);
            GLD_LDS16(gB[c] + k0, lB[c]);
        }
        __syncthreads();

        bf16x8 af[4], bfr[4];
#pragma unroll
        for (int i = 0; i < 4; i++) {
            af[i]  = *(const bf16x8*)&As[rA + i * 1024 + gsel0];
            bfr[i] = *(const bf16x8*)&Bs[rB + i * 1024 + gsel0];
        }
#pragma unroll
        for (int i = 0; i < 4; i++)
#pragma unroll
            for (int j = 0; j < 4; j++)
                acc[i][j] = __builtin_amdgcn_mfma_f32_16x16x32_bf16(af[i], bfr[j], acc[i][j], 0, 0, 0);
#pragma unroll
        for (int i = 0; i < 4; i++) {
            af[i]  = *(const bf16x8*)&As[rA + i * 1024 + gsel1];
            bfr[i] = *(const bf16x8*)&Bs[rB + i * 1024 + gsel1];
        }
#pragma unroll
        for (int i = 0; i < 4; i++)
#pragma unroll
            for (int j = 0; j < 4; j++)
                acc[i][j] = __builtin_amdgcn_mfma_f32_16x16x32_bf16(af[i], bfr[j], acc[i][j], 0, 0, 0);
    }

#pragma unroll
    for (int i = 0; i < 4; i++)
#pragma unroll
        for (int j = 0; j < 4; j++)
#pragma unroll
            for (int r = 0; r < 4; r++) {
                int row = m0 + wr + i * 16 + q4 * 4 + r;
                int col = n0 + wc + j * 16 + l16;
                obf[((size_t)b * 512 + row) * (size_t)N + col] = __float2bfloat16(acc[i][j][r]);
            }
}

// ---------------- ctx partials: ctxp[kc][b][h][d][e] = sum_{n in kc} exp(k[d,n])*v[e,n]
//                  + row sums S_part[kc][b][h][d] = sum_n exp(k[d,n])  (no rowstat, no atomics)
__global__ __launch_bounds__(256) void ctx_kernel(const __hip_bfloat16* __restrict__ kraw,
                                                  const __hip_bfloat16* __restrict__ v,
                                                  float* __restrict__ ctxp,
                                                  float* __restrict__ sums) {
    int kc = blockIdx.x, h = blockIdx.y, b = blockIdx.z;  // kc 0..3
    int t = threadIdx.x, lane = t & 63, wv = t >> 6;
    int l16 = lane & 15, q4 = lane >> 4;
    const __hip_bfloat16* ka = kraw + ((size_t)b * 512 + h * 64) * L_;
    const __hip_bfloat16* va = v + ((size_t)b * 512 + h * 64) * L_;

    f32x4 acc[4][4] = {};
    float ps[4] = {0.f, 0.f, 0.f, 0.f};
    int nbase = kc * 1024 + wv * 256;
#pragma unroll 1
    for (int s = 0; s < 8; s++) {
        int n = nbase + s * 32 + q4 * 8;
        bf16x8 af[4], bfr[4];
#pragma unroll
        for (int i = 0; i < 4; i++) {
            bf16x8 kv = *(const bf16x8*)(ka + (size_t)(i * 16 + l16) * L_ + n);
#pragma unroll
            for (int e = 0; e < 8; e++) {
                float ev = __expf((float)kv[e]);
                af[i][e] = (__bf16)ev;
                ps[i] += ev;
            }
            bfr[i] = *(const bf16x8*)(va + (size_t)(i * 16 + l16) * L_ + n);
        }
#pragma unroll
        for (int i = 0; i < 4; i++)
#pragma unroll
            for (int j = 0; j < 4; j++)
                acc[i][j] = __builtin_amdgcn_mfma_f32_16x16x32_bf16(af[i], bfr[j], acc[i][j], 0, 0, 0);
    }

    // row-sum reduce: over q4 (lanes ^16, ^32), then over waves via LDS
    __shared__ float sred[4][64];
#pragma unroll
    for (int i = 0; i < 4; i++) {
        ps[i] += __shfl_xor(ps[i], 16, 64);
        ps[i] += __shfl_xor(ps[i], 32, 64);
    }
    if (q4 == 0) {
#pragma unroll
        for (int i = 0; i < 4; i++) sred[wv][i * 16 + l16] = ps[i];
    }
    __syncthreads();
    if (t < 64) {
        float S = sred[0][t] + sred[1][t] + sred[2][t] + sred[3][t];
        sums[(((size_t)kc * 8 + b) * 8 + h) * 64 + t] = S;
    }

    // merge 4 waves' acc into cbuf, then plain store to partial buffer
    __shared__ float cbuf[4096];
    for (int w = 0; w < 4; w++) {
        if (wv == w) {
#pragma unroll
            for (int i = 0; i < 4; i++)
#pragma unroll
                for (int j = 0; j < 4; j++)
#pragma unroll
                    for (int r = 0; r < 4; r++) {
                        int mm = i * 16 + q4 * 4 + r, nn = j * 16 + l16;
                        float pv = acc[i][j][r];
                        if (w == 0) cbuf[mm * 64 + nn] = pv;
                        else        cbuf[mm * 64 + nn] += pv;
                    }
        }
        __syncthreads();
    }
    float* cg = ctxp + (((size_t)kc * 8 + b) * 8 + h) * 4096;
    for (int i = t; i < 4096; i += 256) cg[i] = cbuf[i];
}

// ---------------- w2[b][o][h*64+d] = (sum_e w_out[o][h*64+e]*ctx[d][e]) / S[d] ----------------
__global__ __launch_bounds__(256) void w2_kernel(const float* __restrict__ wout,
                                                 const float* __restrict__ ctxp,
                                                 const float* __restrict__ sums,
                                                 __hip_bfloat16* __restrict__ w2) {
    int ob = blockIdx.x, h = blockIdx.y, b = blockIdx.z;
    __shared__ float cT[64 * 65];  // [e][d]
    __shared__ float wT[64 * 65];  // [e][ol]
    __shared__ float Sinv[64];
    int t = threadIdx.x;
    const size_t KCS = (size_t)8 * 8 * 4096;  // kc stride in ctxp (floats)
    const float* cg = ctxp + (((size_t)b) * 8 + h) * 4096;
    for (int i = t; i < 4096; i += 256) {
        int d = i >> 6, e = i & 63;
        float s = cg[i] + cg[KCS + i] + cg[2 * KCS + i] + cg[3 * KCS + i];
        cT[e * 65 + d] = s;
        wT[e * 65 + d] = wout[(size_t)(ob * 64 + d) * 512 + h * 64 + e];
    }
    if (t < 64) {
        const size_t SKC = (size_t)8 * 8 * 64;
        const float* sg = sums + ((size_t)b * 8 + h) * 64;
        float S = sg[t] + sg[SKC + t] + sg[2 * SKC + t] + sg[3 * SKC + t];
        Sinv[t] = 1.0f / S;
    }
    __syncthreads();
    int ol = t >> 2;
    int db = (t & 3) * 16;
    for (int dd = 0; dd < 16; dd++) {
        int d = db + dd;
        float s = 0.f;
#pragma unroll
        for (int e = 0; e < 64; e++) s += wT[e * 65 + ol] * cT[e * 65 + d];
        w2[((size_t)b * 512 + ob * 64 + ol) * 512 + h * 64 + d] = __float2bfloat16(s * Sinv[d]);
    }
}

// ---------------- launch ----------------
extern "C" void kernel_launch(void* const* d_in, const int* in_sizes, int n_in,
                              void* d_out, int out_size, void* d_ws, size_t ws_size,
                              hipStream_t stream) {
    const float* x     = (const float*)d_in[0];
    const float* w_qkv = (const float*)d_in[1];
    const float* w_out = (const float*)d_in[2];
    const float* b_out = (const float*)d_in[3];
    float* out = (float*)d_out;
    char* ws = (char*)d_ws;

    const size_t QKV = (size_t)B_ * 512 * L_;
    size_t off_xt   = 0;                                    // bf16 [b][L][C]   32 MiB
    size_t off_wkv  = off_xt + (size_t)B_ * L_ * C_ * 2;    // bf16 1024x512     1 MiB
    size_t off_wqT  = off_wkv + (size_t)1024 * 512 * 2;     // bf16 512x512    0.5 MiB
    size_t off_k    = off_wqT + (size_t)512 * 512 * 2;      // bf16             32 MiB
    size_t off_v    = off_k + QKV * 2;                      // bf16             32 MiB
    size_t off_ctxp = off_v + QKV * 2;                      // fp32 4x8x8x4096   4 MiB
    size_t off_sums = off_ctxp + (size_t)4 * 8 * 8 * 4096 * 4;  // fp32         64 KiB
    // w2 / W3 overlay the dead kb region (kb fully consumed by ctx before w2 writes)
    size_t off_w2   = off_k;                                // bf16 8x512x512    4 MiB
    size_t off_w3   = off_k + (size_t)B_ * 512 * 512 * 2;   // bf16              4 MiB

    __hip_bfloat16* xt   = (__hip_bfloat16*)(ws + off_xt);
    __hip_bfloat16* wkvb = (__hip_bfloat16*)(ws + off_wkv);
    __hip_bfloat16* wqT  = (__hip_bfloat16*)(ws + off_wqT);
    __hip_bfloat16* kb   = (__hip_bfloat16*)(ws + off_k);
    __hip_bfloat16* vb   = (__hip_bfloat16*)(ws + off_v);
    float*          ctxp = (float*)(ws + off_ctxp);
    float*          sums = (float*)(ws + off_sums);
    __hip_bfloat16* w2   = (__hip_bfloat16*)(ws + off_w2);
    __hip_bfloat16* W3   = (__hip_bfloat16*)(ws + off_w3);

    prep_all<<<4352, 256, 0, stream>>>(x, xt, w_qkv, wkvb, wqT);

    // k,v = Wkv @ x   (M=1024, N=4096, K=512 per batch) — 128^2 pipelined, 2 blk/CU
    gemm_p<1><<<dim3(L_ / 128, 1024 / 128, B_), 256, 0, stream>>>(
        wkvb, xt, 0, (size_t)L_ * C_, 1024, L_, 512, kb, vb, nullptr, nullptr);

    // ctx partials + row sums (kc = 4)
    ctx_kernel<<<dim3(4, 8, B_), 256, 0, stream>>>(kb, vb, ctxp, sums);

    w2_kernel<<<dim3(8, 8, B_), 256, 0, stream>>>(w_out, ctxp, sums, w2);

    // W3[b] = w2[b] @ Wq   (M=512, N=512, K=512)
    gemm_bt<3><<<dim3(512 / 128, 512 / 128, B_), 256, 0, stream>>>(
        w2, wqT, (size_t)512 * 512, 0, 512, 512, 512, W3);

    // out = W3[b] @ x[b] + b_out   (M=512, N=4096, K=512) — 128^2 pipelined
    gemm_p<2><<<dim3(L_ / 128, 512 / 128, B_), 256, 0, stream>>>(
        W3, xt, (size_t)512 * 512, (size_t)L_ * C_, 512, L_, 512, nullptr, nullptr, out, b_out);
}